// Round 5
// baseline (412.346 us; speedup 1.0000x reference)
//
#include <hip/hip_runtime.h>
#include <stdint.h>

#define M_DIM 8192
#define N_DIM 4096
#define K_DIM 4224
#define BK 64

typedef float f32x16 __attribute__((ext_vector_type(16)));
typedef int   i32x8  __attribute__((ext_vector_type(8)));
typedef int   i32x4  __attribute__((ext_vector_type(4)));

#define RAW_BARRIER()  asm volatile("s_barrier" ::: "memory")
#define WAIT_VM6()     asm volatile("s_waitcnt vmcnt(6)" ::: "memory")
#define WAIT_VM4()     asm volatile("s_waitcnt vmcnt(4)" ::: "memory")
#define WAIT_VM0()     asm volatile("s_waitcnt vmcnt(0)" ::: "memory")

// ---------------------------------------------------------------------------
// fp4(e2m1) nibble + per-16 E8M0 scale -> exact bf8(e5m2), pure VALU.
// ---------------------------------------------------------------------------
__device__ __forceinline__ uint32_t conv4(uint32_t x, uint32_t k1) {
    uint32_t n7   = x & 0x07070707u;
    uint32_t base = __builtin_amdgcn_perm(0x46444240u, 0x3E3C3800u, n7);
    uint32_t nz   = __builtin_amdgcn_perm(0x01010101u, 0x01010100u, n7);
    uint32_t sign = (x & 0x08080808u) << 4;
    return (base + nz * k1 - (nz << 6)) | sign;
}

__global__ __launch_bounds__(256) void dequant_all(
    const int* __restrict__ Ap, const int* __restrict__ SFA, uint8_t* __restrict__ Aout,
    const int* __restrict__ Bp, const int* __restrict__ SFB, uint8_t* __restrict__ Bout)
{
    const int nblkA = M_DIM * K_DIM / 16;
    int i = blockIdx.x * 256 + threadIdx.x;
    const int* p; const int* sf; uint8_t* out; int idx;
    if (i < nblkA) { p = Ap; sf = SFA; out = Aout; idx = i; }
    else           { p = Bp; sf = SFB; out = Bout; idx = i - nblkA; }

    const int4* p4 = (const int4*)p;
    int4 p0 = p4[2 * idx];
    int4 p1 = p4[2 * idx + 1];
    int s4 = (sf[idx] - 127) << 2;
    uint32_t k1 = (uint32_t)(s4 + 64);

    uint32_t o[4];
#pragma unroll
    for (int g = 0; g < 2; ++g) {
        int4 pg = g ? p1 : p0;
        uint32_t w = (uint32_t)(pg.x & 0xFF) | ((uint32_t)(pg.y & 0xFF) << 8) |
                     ((uint32_t)(pg.z & 0xFF) << 16) | ((uint32_t)pg.w << 24);
        uint32_t lr = conv4(w & 0x0F0F0F0Fu, k1);
        uint32_t hr = conv4((w >> 4) & 0x0F0F0F0Fu, k1);
        o[2 * g]     = __builtin_amdgcn_perm(hr, lr, 0x05010400u); // elems 0..3
        o[2 * g + 1] = __builtin_amdgcn_perm(hr, lr, 0x07030602u); // elems 4..7
    }
    *(uint4*)(out + (size_t)idx * 16) = make_uint4(o[0], o[1], o[2], o[3]);
}

// ---------------------------------------------------------------------------
// GEMM via MX-scaled MFMA at unity scale: C = scale*(A.B^T) + bias
// 256x256 tile, 8 waves (2Mx4N), BK=64, bf8 operands.
// Round-4: B OPERANDS DIRECT FROM GLOBAL (L2) TO REGISTERS.
// r3 post-mortem: LDS pipe saturated (~1800cy demand vs 1100cy MFMA floor;
// 96KB reads + 32KB DMA writes + 384cy/tile measured conflicts). A wave's
// B-fragment is 32 CONTIGUOUS bytes/lane (row bn0+wn*64+ni*32+r31, k-bytes
// [t*64+h*32,+32)) -> one i32x8 global load, issued one iteration ahead.
// Removes 32KB reads + 16KB writes of LDS traffic per tile -> LDS ~1100cy,
// balanced with MFMA. B is wave-private: needs only per-wave vmcnt, no
// barrier. A stays LDS-staged (4x reuse): 4 buffers x 16KB = 64KB.
// Per-iter vmem issue order: {A-stage(t+3):2, B(t+1):4}; vmcnt(6) before
// cluster0 drains exactly {A(t+2), B(t)}. A(t+1) reads mid-iter are safe:
// A(t+1) drained by iter(t-1)'s vmcnt + barrier(t-1) (global confirm).
// Buffer overwrite safe: stage(t+3) targets buf (t-1)%4, read in iter t-2,
// two barriers ago. afY needs no ping-pong (consumed before rewrite).
// ---------------------------------------------------------------------------
__global__ __launch_bounds__(512, 2) void gemm_mx(
    const uint8_t* __restrict__ A, const uint8_t* __restrict__ B,
    const float* __restrict__ scale, const float* __restrict__ bias,
    float* __restrict__ C)
{
    __shared__ uint8_t smem[65536];
    // A-only buffers: buf k at k*16384, each [256 rows][64 k-bytes]

    const int tid  = threadIdx.x;
    const int lane = tid & 63;
    const int w    = tid >> 6;      // 0..7
    const int wm   = w >> 2;        // 0..1 : 128-row band
    const int wn   = w & 3;         // 0..3 : 64-col band
    const int r31  = lane & 31;
    const int h    = lane >> 5;

    // XCD-aware swizzle: 512 blocks total, chunk of 64 consecutive per XCD
    const int lin = blockIdx.y * 16 + blockIdx.x;        // gridDim.x == 16
    const int o   = (lin & 7) * 64 + (lin >> 3);         // bijective (512 % 8 == 0)
    const int bn0 = (o & 15) * 256;
    const int bm0 = (o >> 4) * 256;

    f32x16 acc[4][2];
#pragma unroll
    for (int i = 0; i < 4; ++i)
#pragma unroll
        for (int j = 0; j < 2; ++j)
            acc[i][j] = (f32x16)(0.0f);

    // A staging: wave w stages rows [w*32, w*32+32), 2 gl_lds of 16 rows x 64B.
    // lane slot = local_row*4 + g''; fetch global granule g = g'' ^ ((row>>1)&3)
    const int srow = lane >> 2;
    const int scol = (((lane & 3) ^ ((lane >> 3) & 3)) << 4);
    const uint8_t* Ag = A + (size_t)(bm0 + w * 32 + srow) * K_DIM + scol;
    uint8_t* Asw = smem + w * 2048;

#define STAGE(koff, boff)                                                        \
    do {                                                                         \
        const uint8_t* ag_ = Ag + (koff);                                        \
        __builtin_amdgcn_global_load_lds(                                        \
            (const __attribute__((address_space(1))) void*)(ag_),                \
            (__attribute__((address_space(3))) void*)(Asw + (boff)), 16, 0, 0);  \
        __builtin_amdgcn_global_load_lds(                                        \
            (const __attribute__((address_space(1))) void*)(ag_ + (size_t)16 * K_DIM), \
            (__attribute__((address_space(3))) void*)(Asw + (boff) + 1024), 16, 0, 0); \
    } while (0)

    // B direct-load bases: frag ni, lane (r31,h) reads 32B at
    // B[bn0 + wn*64 + ni*32 + r31][t*64 + h*32 .. +32)
    const uint8_t* pgB0 = B + (size_t)(bn0 + wn * 64 + r31) * K_DIM + h * 32;
    const uint8_t* pgB1 = pgB0 + (size_t)32 * K_DIM;

    // swizzled, kt-invariant A fragment addresses (buf0; bufk = +k*16384)
    const int sx = (r31 >> 1) & 3;
    const uint8_t* pa_lo[4]; const uint8_t* pa_hi[4];
#pragma unroll
    for (int mi = 0; mi < 4; ++mi) {
        const uint8_t* base = smem + (wm * 128 + mi * 32 + r31) * 64;
        pa_lo[mi] = base + (((2 * h)     ^ sx) << 4);
        pa_hi[mi] = base + (((2 * h + 1) ^ sx) << 4);
    }

    i32x8 afX0[2], afX1[2], bfX0[2], bfX1[2], afY[2];

    auto rd = [&](const uint8_t* plo, const uint8_t* phi, int off, i32x8& dst) {
        i32x4 lo = *(const i32x4*)(plo + off);
        i32x4 hi = *(const i32x4*)(phi + off);
        dst = __builtin_shufflevector(lo, hi, 0, 1, 2, 3, 4, 5, 6, 7);
    };
    auto mm = [&](const i32x8& a, const i32x8& b, f32x16& c) {
        c = __builtin_amdgcn_mfma_scale_f32_32x32x64_f8f6f4(
                a, b, c, 1, 1, 0, 0x7F7F7F7F, 0, 0x7F7F7F7F);
    };

// iteration t: B(t+1) global loads issued at top (latency ~= full iter);
// cluster0 on (AC,BC); A01(t+1) ds_reads; cluster1 on (afY,BC); afY(t+1).
#define CORE(AC, BC, AN, BN, OBN, TN)                         \
    BN[0] = *(const i32x8*)(pgB0 + (TN) * 64);                \
    BN[1] = *(const i32x8*)(pgB1 + (TN) * 64);                \
    WAIT_VM6();                                               \
    __builtin_amdgcn_s_setprio(1);                            \
    mm(AC[0], BC[0], acc[0][0]); mm(AC[0], BC[1], acc[0][1]); \
    mm(AC[1], BC[0], acc[1][0]); mm(AC[1], BC[1], acc[1][1]); \
    __builtin_amdgcn_s_setprio(0);                            \
    rd(pa_lo[0], pa_hi[0], OBN, AN[0]);                       \
    rd(pa_lo[1], pa_hi[1], OBN, AN[1]);                       \
    __builtin_amdgcn_s_setprio(1);                            \
    mm(afY[0], BC[0], acc[2][0]); mm(afY[0], BC[1], acc[2][1]); \
    mm(afY[1], BC[0], acc[3][0]); mm(afY[1], BC[1], acc[3][1]); \
    __builtin_amdgcn_s_setprio(0);                            \
    rd(pa_lo[2], pa_hi[2], OBN, afY[0]);                      \
    rd(pa_lo[3], pa_hi[3], OBN, afY[1]);

#define BODY(T, AC, BC, AN, BN, OBN, OBS)                     \
    STAGE(((T) + 3) * BK, OBS);                               \
    CORE(AC, BC, AN, BN, OBN, (T) + 1)                        \
    RAW_BARRIER();

    // prologue: stage A tiles 0,1,2 -> buf0,1,2; load B(0); drain; barrier.
    STAGE(0 * BK, 0);
    STAGE(1 * BK, 16384);
    STAGE(2 * BK, 32768);
    bfX0[0] = *(const i32x8*)(pgB0 + 0);
    bfX0[1] = *(const i32x8*)(pgB1 + 0);
    WAIT_VM0();
    RAW_BARRIER();
    rd(pa_lo[0], pa_hi[0], 0, afX0[0]);
    rd(pa_lo[1], pa_hi[1], 0, afX0[1]);
    rd(pa_lo[2], pa_hi[2], 0, afY[0]);
    rd(pa_lo[3], pa_hi[3], 0, afY[1]);

    // main: t = 0..59, unroll 4 (A-buf of t+1 = (t+1)%4, stage buf = (t+3)%4)
#pragma unroll 1
    for (int g = 0; g < 15; ++g) {
        const int t = 4 * g;
        BODY(t,     afX0, bfX0, afX1, bfX1, 16384, 49152)
        BODY(t + 1, afX1, bfX1, afX0, bfX0, 32768, 0)
        BODY(t + 2, afX0, bfX0, afX1, bfX1, 49152, 16384)
        BODY(t + 3, afX1, bfX1, afX0, bfX0, 0,     32768)
    }
    // tail: t = 60,61,62 still stage tiles 63,64,65
    BODY(60, afX0, bfX0, afX1, bfX1, 16384, 49152)
    BODY(61, afX1, bfX1, afX0, bfX0, 32768, 0)
    BODY(62, afX0, bfX0, afX1, bfX1, 49152, 16384)
    // t=63: no stage. Loads B(64); vmcnt(4) drains {A(65), B(63)}.
    bfX0[0] = *(const i32x8*)(pgB0 + 64 * 64);
    bfX0[1] = *(const i32x8*)(pgB1 + 64 * 64);
    WAIT_VM4();
    __builtin_amdgcn_s_setprio(1);
    mm(afX1[0], bfX1[0], acc[0][0]); mm(afX1[0], bfX1[1], acc[0][1]);
    mm(afX1[1], bfX1[0], acc[1][0]); mm(afX1[1], bfX1[1], acc[1][1]);
    __builtin_amdgcn_s_setprio(0);
    rd(pa_lo[0], pa_hi[0], 0, afX0[0]);
    rd(pa_lo[1], pa_hi[1], 0, afX0[1]);
    __builtin_amdgcn_s_setprio(1);
    mm(afY[0], bfX1[0], acc[2][0]); mm(afY[0], bfX1[1], acc[2][1]);
    mm(afY[1], bfX1[0], acc[3][0]); mm(afY[1], bfX1[1], acc[3][1]);
    __builtin_amdgcn_s_setprio(0);
    rd(pa_lo[2], pa_hi[2], 0, afY[0]);
    rd(pa_lo[3], pa_hi[3], 0, afY[1]);
    RAW_BARRIER();
    // t=64: loads B(65); vmcnt(4) drains B(64). A(65) in buf1 (+16384).
    bfX1[0] = *(const i32x8*)(pgB0 + 65 * 64);
    bfX1[1] = *(const i32x8*)(pgB1 + 65 * 64);
    WAIT_VM4();
    __builtin_amdgcn_s_setprio(1);
    mm(afX0[0], bfX0[0], acc[0][0]); mm(afX0[0], bfX0[1], acc[0][1]);
    mm(afX0[1], bfX0[0], acc[1][0]); mm(afX0[1], bfX0[1], acc[1][1]);
    __builtin_amdgcn_s_setprio(0);
    rd(pa_lo[0], pa_hi[0], 16384, afX1[0]);
    rd(pa_lo[1], pa_hi[1], 16384, afX1[1]);
    __builtin_amdgcn_s_setprio(1);
    mm(afY[0], bfX0[0], acc[2][0]); mm(afY[0], bfX0[1], acc[2][1]);
    mm(afY[1], bfX0[0], acc[3][0]); mm(afY[1], bfX0[1], acc[3][1]);
    __builtin_amdgcn_s_setprio(0);
    rd(pa_lo[2], pa_hi[2], 16384, afY[0]);
    rd(pa_lo[3], pa_hi[3], 16384, afY[1]);
    // t=65: drain B(65); final clusters (no staging, no barrier).
    WAIT_VM0();
    __builtin_amdgcn_s_setprio(1);
    mm(afX1[0], bfX1[0], acc[0][0]); mm(afX1[0], bfX1[1], acc[0][1]);
    mm(afX1[1], bfX1[0], acc[1][0]); mm(afX1[1], bfX1[1], acc[1][1]);
    mm(afY[0],  bfX1[0], acc[2][0]); mm(afY[0],  bfX1[1], acc[2][1]);
    mm(afY[1],  bfX1[0], acc[3][0]); mm(afY[1],  bfX1[1], acc[3][1]);
    __builtin_amdgcn_s_setprio(0);
#undef BODY
#undef CORE
#undef STAGE

    const float sc = scale[0];
#pragma unroll
    for (int ni = 0; ni < 2; ++ni) {
        const int col = bn0 + wn * 64 + ni * 32 + r31;
        const float bv = bias[col];
#pragma unroll
        for (int mi = 0; mi < 4; ++mi) {
            const int rbase = bm0 + wm * 128 + mi * 32 + 4 * h;
#pragma unroll
            for (int reg = 0; reg < 16; ++reg) {
                const int row = rbase + (reg & 3) + 8 * (reg >> 2);
                C[(size_t)row * N_DIM + col] = sc * acc[mi][ni][reg] + bv;
            }
        }
    }
}

extern "C" void kernel_launch(void* const* d_in, const int* in_sizes, int n_in,
                              void* d_out, int out_size, void* d_ws, size_t ws_size,
                              hipStream_t stream) {
    const int*   A_packed = (const int*)d_in[0];
    const int*   SFA      = (const int*)d_in[1];
    const float* scale    = (const float*)d_in[2];
    const int*   B_packed = (const int*)d_in[3];
    const int*   SFB      = (const int*)d_in[4];
    const float* bias     = (const float*)d_in[5];
    float*       out      = (float*)d_out;

    uint8_t* Abf8 = (uint8_t*)d_ws;
    uint8_t* Bbf8 = Abf8 + (size_t)M_DIM * K_DIM;

    const int nblkA = M_DIM * K_DIM / 16;   // 2,162,688 (8448 blocks of 256)
    const int nblkB = N_DIM * K_DIM / 16;   // 1,081,344 (4224 blocks)
    dequant_all<<<(nblkA + nblkB) / 256, 256, 0, stream>>>(
        A_packed, SFA, Abf8, B_packed, SFB, Bbf8);

    dim3 grid(N_DIM / 256, M_DIM / 256);    // (16, 32) = 512 blocks
    gemm_mx<<<grid, 512, 0, stream>>>(Abf8, Bbf8, scale, bias, out);
}

// Round 6
// 340.367 us; speedup vs baseline: 1.2115x; 1.2115x over previous
//
#include <hip/hip_runtime.h>
#include <stdint.h>

#define M_DIM 8192
#define N_DIM 4096
#define K_DIM 4224
#define BK 64

typedef float f32x16 __attribute__((ext_vector_type(16)));
typedef int   i32x8  __attribute__((ext_vector_type(8)));
typedef int   i32x4  __attribute__((ext_vector_type(4)));

#define RAW_BARRIER()  asm volatile("s_barrier" ::: "memory")
#define WAIT_VM4()     asm volatile("s_waitcnt vmcnt(4)" ::: "memory")
#define WAIT_VM0()     asm volatile("s_waitcnt vmcnt(0)" ::: "memory")

// ---------------------------------------------------------------------------
// fp4(e2m1) nibble + per-16 E8M0 scale -> exact bf8(e5m2), pure VALU.
// ---------------------------------------------------------------------------
__device__ __forceinline__ uint32_t conv4(uint32_t x, uint32_t k1) {
    uint32_t n7   = x & 0x07070707u;
    uint32_t base = __builtin_amdgcn_perm(0x46444240u, 0x3E3C3800u, n7);
    uint32_t nz   = __builtin_amdgcn_perm(0x01010101u, 0x01010100u, n7);
    uint32_t sign = (x & 0x08080808u) << 4;
    return (base + nz * k1 - (nz << 6)) | sign;
}

// Round-5 dequant: 32 elements (2 scale-blocks) per thread.
// 4x16B contiguous loads + int2 scale load -> 2x independent-load MLP of the
// old version; 2x16B stores. If the old dequant was latency-bound (only 2
// loads in flight), this halves its duration; if it was BW-bound (~27us),
// this is neutral and the total-vs-gemm gap is fixed harness overhead.
__global__ __launch_bounds__(256) void dequant_all(
    const int* __restrict__ Ap, const int* __restrict__ SFA, uint8_t* __restrict__ Aout,
    const int* __restrict__ Bp, const int* __restrict__ SFB, uint8_t* __restrict__ Bout)
{
    const int nhA = M_DIM * K_DIM / 32;     // A pair-count (2 blocks = 32 elems)
    int i = blockIdx.x * 256 + threadIdx.x;
    const int* p; const int* sf; uint8_t* out; int idx;
    if (i < nhA) { p = Ap; sf = SFA; out = Aout; idx = i; }
    else         { p = Bp; sf = SFB; out = Bout; idx = i - nhA; }

    const int4* p4 = (const int4*)p;
    int4 q0 = p4[4 * idx];
    int4 q1 = p4[4 * idx + 1];
    int4 q2 = p4[4 * idx + 2];
    int4 q3 = p4[4 * idx + 3];
    int2 sfp = ((const int2*)sf)[idx];
    uint32_t k1a = (uint32_t)(((sfp.x - 127) << 2) + 64);
    uint32_t k1b = (uint32_t)(((sfp.y - 127) << 2) + 64);

    uint32_t o[8];
#pragma unroll
    for (int g = 0; g < 4; ++g) {
        int4 pg = (g == 0) ? q0 : (g == 1) ? q1 : (g == 2) ? q2 : q3;
        uint32_t k1 = (g < 2) ? k1a : k1b;
        uint32_t w = (uint32_t)(pg.x & 0xFF) | ((uint32_t)(pg.y & 0xFF) << 8) |
                     ((uint32_t)(pg.z & 0xFF) << 16) | ((uint32_t)pg.w << 24);
        uint32_t lr = conv4(w & 0x0F0F0F0Fu, k1);
        uint32_t hr = conv4((w >> 4) & 0x0F0F0F0Fu, k1);
        o[2 * g]     = __builtin_amdgcn_perm(hr, lr, 0x05010400u); // elems 0..3
        o[2 * g + 1] = __builtin_amdgcn_perm(hr, lr, 0x07030602u); // elems 4..7
    }
    *(uint4*)(out + (size_t)idx * 32)      = make_uint4(o[0], o[1], o[2], o[3]);
    *(uint4*)(out + (size_t)idx * 32 + 16) = make_uint4(o[4], o[5], o[6], o[7]);
}

// ---------------------------------------------------------------------------
// GEMM via MX-scaled MFMA at unity scale: C = scale*(A.B^T) + bias
// 256x256 tile, 8 waves (2Mx4N), BK=64, bf8 operands.
// Round-3 schedule (best measured: 133us, MfmaUtil 49): FULL READ-AHEAD.
// All 6 fragments of tile t+1 are read during iteration t, split around the
// two MFMA clusters. Post-barrier path is STAGE -> cluster0 with ZERO lgkm
// dependency. r4's B-direct-from-global variant REGRESSED (216us): 64-row
// scatter loads amplified L2 line-requests 16x — B stays LDS-staged.
// Residency: stage-ahead-3 + vmcnt(4)/iter confirms tile t+2 pre-barrier =>
// reads of t+1 during iter t are globally confirmed one barrier earlier.
// Buffer safety: STAGE(t+3) targets buf (t-1)%4, read during iter t-2.
// ---------------------------------------------------------------------------
__global__ __launch_bounds__(512, 2) void gemm_mx(
    const uint8_t* __restrict__ A, const uint8_t* __restrict__ B,
    const float* __restrict__ scale, const float* __restrict__ bias,
    float* __restrict__ C)
{
    __shared__ uint8_t smem[131072];
    // buf k at offset k*32768: A [256][64] at +0, B [256][64] at +16384

    const int tid  = threadIdx.x;
    const int lane = tid & 63;
    const int w    = tid >> 6;      // 0..7
    const int wm   = w >> 2;        // 0..1 : 128-row band
    const int wn   = w & 3;         // 0..3 : 64-col band
    const int r31  = lane & 31;
    const int h    = lane >> 5;

    // XCD-aware swizzle: 512 blocks total, chunk of 64 consecutive per XCD
    const int lin = blockIdx.y * 16 + blockIdx.x;        // gridDim.x == 16
    const int o   = (lin & 7) * 64 + (lin >> 3);         // bijective (512 % 8 == 0)
    const int bn0 = (o & 15) * 256;
    const int bm0 = (o >> 4) * 256;

    f32x16 acc[4][2];
#pragma unroll
    for (int i = 0; i < 4; ++i)
#pragma unroll
        for (int j = 0; j < 2; ++j)
            acc[i][j] = (f32x16)(0.0f);

    // staging: wave w stages rows [w*32, w*32+32) of A and of B,
    // 2 issues of 16 rows x 64B per matrix (4 global_load_lds per wave per tile).
    const int srow = lane >> 2;
    const int scol = (((lane & 3) ^ ((lane >> 3) & 3)) << 4);
    const uint8_t* Ag = A + (size_t)(bm0 + w * 32 + srow) * K_DIM + scol;
    const uint8_t* Bg = B + (size_t)(bn0 + w * 32 + srow) * K_DIM + scol;
    uint8_t* Asw = smem + w * 2048;
    uint8_t* Bsw = smem + 16384 + w * 2048;

#define STAGE(koff, boff)                                                        \
    do {                                                                         \
        const uint8_t* ag_ = Ag + (koff);                                        \
        const uint8_t* bg_ = Bg + (koff);                                        \
        __builtin_amdgcn_global_load_lds(                                        \
            (const __attribute__((address_space(1))) void*)(ag_),                \
            (__attribute__((address_space(3))) void*)(Asw + (boff)), 16, 0, 0);  \
        __builtin_amdgcn_global_load_lds(                                        \
            (const __attribute__((address_space(1))) void*)(ag_ + (size_t)16 * K_DIM), \
            (__attribute__((address_space(3))) void*)(Asw + (boff) + 1024), 16, 0, 0); \
        __builtin_amdgcn_global_load_lds(                                        \
            (const __attribute__((address_space(1))) void*)(bg_),                \
            (__attribute__((address_space(3))) void*)(Bsw + (boff)), 16, 0, 0);  \
        __builtin_amdgcn_global_load_lds(                                        \
            (const __attribute__((address_space(1))) void*)(bg_ + (size_t)16 * K_DIM), \
            (__attribute__((address_space(3))) void*)(Bsw + (boff) + 1024), 16, 0, 0); \
    } while (0)

    // swizzled, kt-invariant fragment addresses (buf0; bufk = +k*32768)
    const int sx = (r31 >> 1) & 3;
    const uint8_t* pa_lo[4]; const uint8_t* pa_hi[4];
    const uint8_t* pb_lo[2]; const uint8_t* pb_hi[2];
#pragma unroll
    for (int mi = 0; mi < 4; ++mi) {
        const uint8_t* base = smem + (wm * 128 + mi * 32 + r31) * 64;
        pa_lo[mi] = base + (((2 * h)     ^ sx) << 4);
        pa_hi[mi] = base + (((2 * h + 1) ^ sx) << 4);
    }
#pragma unroll
    for (int ni = 0; ni < 2; ++ni) {
        const uint8_t* base = smem + 16384 + (wn * 64 + ni * 32 + r31) * 64;
        pb_lo[ni] = base + (((2 * h)     ^ sx) << 4);
        pb_hi[ni] = base + (((2 * h + 1) ^ sx) << 4);
    }

    i32x8 afX0[2], afX1[2], bfX0[2], bfX1[2], afY[2];

    auto rd = [&](const uint8_t* plo, const uint8_t* phi, int off, i32x8& dst) {
        i32x4 lo = *(const i32x4*)(plo + off);
        i32x4 hi = *(const i32x4*)(phi + off);
        dst = __builtin_shufflevector(lo, hi, 0, 1, 2, 3, 4, 5, 6, 7);
    };
    auto mm = [&](const i32x8& a, const i32x8& b, f32x16& c) {
        c = __builtin_amdgcn_mfma_scale_f32_32x32x64_f8f6f4(
                a, b, c, 1, 1, 0, 0x7F7F7F7F, 0, 0x7F7F7F7F);
    };

// iteration t (read-ahead): cluster0 on (AC,BC) [read during t-1];
// read af01/bf01(t+1)->AN/BN; cluster1 on (afY,BC); read af23(t+1)->afY.
#define CORE(AC, BC, AN, BN, OBN)                             \
    __builtin_amdgcn_s_setprio(1);                            \
    mm(AC[0], BC[0], acc[0][0]); mm(AC[0], BC[1], acc[0][1]); \
    mm(AC[1], BC[0], acc[1][0]); mm(AC[1], BC[1], acc[1][1]); \
    __builtin_amdgcn_s_setprio(0);                            \
    rd(pa_lo[0], pa_hi[0], OBN, AN[0]);                       \
    rd(pa_lo[1], pa_hi[1], OBN, AN[1]);                       \
    rd(pb_lo[0], pb_hi[0], OBN, BN[0]);                       \
    rd(pb_lo[1], pb_hi[1], OBN, BN[1]);                       \
    __builtin_amdgcn_s_setprio(1);                            \
    mm(afY[0], BC[0], acc[2][0]); mm(afY[0], BC[1], acc[2][1]); \
    mm(afY[1], BC[0], acc[3][0]); mm(afY[1], BC[1], acc[3][1]); \
    __builtin_amdgcn_s_setprio(0);                            \
    rd(pa_lo[2], pa_hi[2], OBN, afY[0]);                      \
    rd(pa_lo[3], pa_hi[3], OBN, afY[1]);

#define BODY(T, AC, BC, AN, BN, OBN, OBS)                     \
    STAGE(((T) + 3) * BK, OBS);                               \
    CORE(AC, BC, AN, BN, OBN)                                 \
    WAIT_VM4(); RAW_BARRIER();

    // prologue: stage tiles 0,1,2 -> buf0,1,2; vmcnt(4) confirms tiles 0 AND 1
    // (globally, via the barrier) so iteration 0 may read-ahead tile 1.
    STAGE(0 * BK, 0);
    STAGE(1 * BK, 32768);
    STAGE(2 * BK, 65536);
    WAIT_VM4();
    RAW_BARRIER();
    // fragments of tile 0 (buf0)
    rd(pa_lo[0], pa_hi[0], 0, afX0[0]);
    rd(pa_lo[1], pa_hi[1], 0, afX0[1]);
    rd(pb_lo[0], pb_hi[0], 0, bfX0[0]);
    rd(pb_lo[1], pb_hi[1], 0, bfX0[1]);
    rd(pa_lo[2], pa_hi[2], 0, afY[0]);
    rd(pa_lo[3], pa_hi[3], 0, afY[1]);

    // main: t = 0..59, unroll 4 (buf of t+1 = (t+1)%4, stage buf = (t+3)%4)
#pragma unroll 1
    for (int g = 0; g < 15; ++g) {
        const int t = 4 * g;
        BODY(t,     afX0, bfX0, afX1, bfX1, 32768, 98304)
        BODY(t + 1, afX1, bfX1, afX0, bfX0, 65536, 0)
        BODY(t + 2, afX0, bfX0, afX1, bfX1, 98304, 32768)
        BODY(t + 3, afX1, bfX1, afX0, bfX0, 0,     65536)
    }
    // tail: t = 60,61,62 still stage (63,64,65)
    BODY(60, afX0, bfX0, afX1, bfX1, 32768, 98304)
    BODY(61, afX1, bfX1, afX0, bfX0, 65536, 0)
    BODY(62, afX0, bfX0, afX1, bfX1, 98304, 32768)
    // t=63: no stage; reads tile 64 (buf0); vmcnt(0) confirms tile 65
    CORE(afX1, bfX1, afX0, bfX0, 0)
    WAIT_VM0(); RAW_BARRIER();
    // t=64: reads tile 65 (buf1); no more LDS writes -> no barrier needed
    CORE(afX0, bfX0, afX1, bfX1, 32768)
    // t=65: clusters only
    __builtin_amdgcn_s_setprio(1);
    mm(afX1[0], bfX1[0], acc[0][0]); mm(afX1[0], bfX1[1], acc[0][1]);
    mm(afX1[1], bfX1[0], acc[1][0]); mm(afX1[1], bfX1[1], acc[1][1]);
    mm(afY[0],  bfX1[0], acc[2][0]); mm(afY[0],  bfX1[1], acc[2][1]);
    mm(afY[1],  bfX1[0], acc[3][0]); mm(afY[1],  bfX1[1], acc[3][1]);
    __builtin_amdgcn_s_setprio(0);
#undef BODY
#undef CORE
#undef STAGE

    const float sc = scale[0];
#pragma unroll
    for (int ni = 0; ni < 2; ++ni) {
        const int col = bn0 + wn * 64 + ni * 32 + r31;
        const float bv = bias[col];
#pragma unroll
        for (int mi = 0; mi < 4; ++mi) {
            const int rbase = bm0 + wm * 128 + mi * 32 + 4 * h;
#pragma unroll
            for (int reg = 0; reg < 16; ++reg) {
                const int row = rbase + (reg & 3) + 8 * (reg >> 2);
                C[(size_t)row * N_DIM + col] = sc * acc[mi][ni][reg] + bv;
            }
        }
    }
}

extern "C" void kernel_launch(void* const* d_in, const int* in_sizes, int n_in,
                              void* d_out, int out_size, void* d_ws, size_t ws_size,
                              hipStream_t stream) {
    const int*   A_packed = (const int*)d_in[0];
    const int*   SFA      = (const int*)d_in[1];
    const float* scale    = (const float*)d_in[2];
    const int*   B_packed = (const int*)d_in[3];
    const int*   SFB      = (const int*)d_in[4];
    const float* bias     = (const float*)d_in[5];
    float*       out      = (float*)d_out;

    uint8_t* Abf8 = (uint8_t*)d_ws;
    uint8_t* Bbf8 = Abf8 + (size_t)M_DIM * K_DIM;

    const int npairA = M_DIM * K_DIM / 32;  // 1,081,344
    const int npairB = N_DIM * K_DIM / 32;  //   540,672
    dequant_all<<<(npairA + npairB) / 256, 256, 0, stream>>>(
        A_packed, SFA, Abf8, B_packed, SFB, Bbf8);   // 6336 blocks

    dim3 grid(N_DIM / 256, M_DIM / 256);    // (16, 32) = 512 blocks
    gemm_mx<<<grid, 512, 0, stream>>>(Abf8, Bbf8, scale, bias, out);
}